// Round 1
// baseline (497.300 us; speedup 1.0000x reference)
//
#include <hip/hip_runtime.h>

#define DEV __device__ __forceinline__

typedef __bf16 bf16x8 __attribute__((ext_vector_type(8)));
typedef float f32x4 __attribute__((ext_vector_type(4)));

constexpr int BROWS = 8192;
constexpr int S = 4;
constexpr int D = 1024;
constexpr int SD = S * D;          // 4096

// ---------------- helpers ----------------
DEV unsigned short f2bf(float f) {  // RNE float->bf16
  unsigned int u = __float_as_uint(f);
  u = (u + 0x7FFFu + ((u >> 16) & 1u)) >> 16;
  return (unsigned short)u;
}

DEV float wred(float v) {  // full 64-lane butterfly sum
#pragma unroll
  for (int m = 1; m < 64; m <<= 1) v += __shfl_xor(v, m);
  return v;
}

DEV float sigmoidf(float x) { return 1.0f / (1.0f + __expf(-x)); }

// ---------------- K0a: row-sums of the 24 gate weight rows ----------------
__global__ __launch_bounds__(256) void k0_wsum(
    const float* __restrict__ Wpre, const float* __restrict__ Wpost,
    const float* __restrict__ Wres, float* __restrict__ wsum) {
  const int j = blockIdx.x;  // 0..23: 0-3 pre, 4-7 post, 8-23 res
  const float* src = (j < 4) ? (Wpre + j * SD)
                             : (j < 8 ? (Wpost + (j - 4) * SD) : (Wres + (j - 8) * SD));
  float s = 0.f;
  for (int i = threadIdx.x * 4; i < SD; i += 1024) {
    float4 v = *(const float4*)(src + i);
    s += v.x + v.y + v.z + v.w;
  }
  s = wred(s);
  __shared__ float tmp[4];
  if ((threadIdx.x & 63) == 0) tmp[threadIdx.x >> 6] = s;
  __syncthreads();
  if (threadIdx.x == 0) wsum[j] = tmp[0] + tmp[1] + tmp[2] + tmp[3];
}

// ---------------- K0b: W_layer fp32 -> bf16 ----------------
__global__ __launch_bounds__(256) void k0_conv(const float* __restrict__ W,
                                               unsigned short* __restrict__ out) {
  const int i = (blockIdx.x * 256 + threadIdx.x) * 4;
  float4 v = *(const float4*)(W + i);
  ushort4 u;
  u.x = f2bf(v.x); u.y = f2bf(v.y); u.z = f2bf(v.z); u.w = f2bf(v.w);
  *(ushort4*)(out + i) = u;
}

// ---------------- K1: fused per-row pass ----------------
// One wave handles 4 rows. Single sweep over x computes sum/sumsq + 24 raw
// dots (LN correction: dot_j = rstd*(raw_j - mu*Wsum_j)). Then lane-parallel
// sinkhorn (64 lanes = 4 rows x 16 entries), then x_agg + LN -> bf16 ln_agg.
__global__ __launch_bounds__(256) void k1_rowpass(
    const float* __restrict__ xs,
    const float* __restrict__ Wpre, const float* __restrict__ bpre,
    const float* __restrict__ Wpost, const float* __restrict__ bpost,
    const float* __restrict__ Wres, const float* __restrict__ bres,
    const float* __restrict__ s_apre, const float* __restrict__ s_apost,
    const float* __restrict__ s_ares,
    const float* __restrict__ gamma, const float* __restrict__ beta,
    const float* __restrict__ wsum,
    unsigned short* __restrict__ lnagg,
    float* __restrict__ hres_g, float* __restrict__ hpost_g) {
  const int tid = threadIdx.x;
  const int wv = tid >> 6;
  const int ln = tid & 63;
  const int rowbase = blockIdx.x * 16 + wv * 4;

  float dpre[4][4];   // [s][r]
  float dpost[4][4];
  float dres[16][4];  // [j][r]
  float sum[4], sq[4];
#pragma unroll
  for (int s = 0; s < 4; ++s)
#pragma unroll
    for (int r = 0; r < 4; ++r) { dpre[s][r] = 0.f; dpost[s][r] = 0.f; }
#pragma unroll
  for (int j = 0; j < 16; ++j)
#pragma unroll
    for (int r = 0; r < 4; ++r) dres[j][r] = 0.f;
#pragma unroll
  for (int r = 0; r < 4; ++r) { sum[r] = 0.f; sq[r] = 0.f; }

  const float* xr0 = xs + (size_t)(rowbase + 0) * SD;
  const float* xr1 = xs + (size_t)(rowbase + 1) * SD;
  const float* xr2 = xs + (size_t)(rowbase + 2) * SD;
  const float* xr3 = xs + (size_t)(rowbase + 3) * SD;

#pragma unroll 1
  for (int it = 0; it < 16; ++it) {
    const int i = it * 256 + ln * 4;
    float4 xv[4];
    xv[0] = *(const float4*)(xr0 + i);
    xv[1] = *(const float4*)(xr1 + i);
    xv[2] = *(const float4*)(xr2 + i);
    xv[3] = *(const float4*)(xr3 + i);
#pragma unroll
    for (int r = 0; r < 4; ++r) {
      sum[r] += xv[r].x + xv[r].y + xv[r].z + xv[r].w;
      sq[r] += xv[r].x * xv[r].x + xv[r].y * xv[r].y + xv[r].z * xv[r].z + xv[r].w * xv[r].w;
    }
#pragma unroll
    for (int s = 0; s < 4; ++s) {
      const float4 w = *(const float4*)(Wpre + s * SD + i);
#pragma unroll
      for (int r = 0; r < 4; ++r)
        dpre[s][r] += w.x * xv[r].x + w.y * xv[r].y + w.z * xv[r].z + w.w * xv[r].w;
    }
#pragma unroll
    for (int s = 0; s < 4; ++s) {
      const float4 w = *(const float4*)(Wpost + s * SD + i);
#pragma unroll
      for (int r = 0; r < 4; ++r)
        dpost[s][r] += w.x * xv[r].x + w.y * xv[r].y + w.z * xv[r].z + w.w * xv[r].w;
    }
#pragma unroll
    for (int j = 0; j < 16; ++j) {
      const float4 w = *(const float4*)(Wres + j * SD + i);
#pragma unroll
      for (int r = 0; r < 4; ++r)
        dres[j][r] += w.x * xv[r].x + w.y * xv[r].y + w.z * xv[r].z + w.w * xv[r].w;
    }
  }

  // wave reductions (all lanes end with totals)
#pragma unroll
  for (int r = 0; r < 4; ++r) { sum[r] = wred(sum[r]); sq[r] = wred(sq[r]); }
#pragma unroll
  for (int s = 0; s < 4; ++s)
#pragma unroll
    for (int r = 0; r < 4; ++r) { dpre[s][r] = wred(dpre[s][r]); dpost[s][r] = wred(dpost[s][r]); }
#pragma unroll
  for (int j = 0; j < 16; ++j)
#pragma unroll
    for (int r = 0; r < 4; ++r) dres[j][r] = wred(dres[j][r]);

  float mu[4], rstd[4];
#pragma unroll
  for (int r = 0; r < 4; ++r) {
    mu[r] = sum[r] * (1.0f / 4096.0f);
    float var = sq[r] * (1.0f / 4096.0f) - mu[r] * mu[r];
    rstd[r] = rsqrtf(var + 1e-5f);
  }
  const float apre = s_apre[0], apost = s_apost[0], ares = s_ares[0];
  float wspre[4], wspost[4];
#pragma unroll
  for (int s = 0; s < 4; ++s) { wspre[s] = wsum[s]; wspost[s] = wsum[4 + s]; }

  float hpre[4][4];  // [r][s]
#pragma unroll
  for (int r = 0; r < 4; ++r) {
#pragma unroll
    for (int s = 0; s < 4; ++s) {
      float dot = rstd[r] * (dpre[s][r] - mu[r] * wspre[s]);
      hpre[r][s] = sigmoidf(apre * (dot + bpre[s]));
      float dot2 = rstd[r] * (dpost[s][r] - mu[r] * wspost[s]);
      float hp = 2.0f * sigmoidf(apost * (dot2 + bpost[s]));
      if (ln == 0) hpost_g[(rowbase + r) * 4 + s] = hp;
    }
  }

  // route res-dots to lanes via LDS, then lane-parallel sinkhorn
  __shared__ float SK[4][64];
  if (ln == 0) {
#pragma unroll
    for (int r = 0; r < 4; ++r)
#pragma unroll
      for (int j = 0; j < 16; ++j)
        SK[wv][r * 16 + j] = rstd[r] * (dres[j][r] - mu[r] * wsum[8 + j]);
  }
  __syncthreads();
  {
    const int rr = ln >> 4, jj = ln & 15;
    float M = __expf(ares * (SK[wv][rr * 16 + jj] + bres[jj]));
#pragma unroll 1
    for (int itr = 0; itr < 20; ++itr) {
      float rs = M + __shfl_xor(M, 1);
      rs += __shfl_xor(rs, 2);
      M *= __builtin_amdgcn_rcpf(rs + 1e-8f);
      float cs = M + __shfl_xor(M, 4);
      cs += __shfl_xor(cs, 8);
      M *= __builtin_amdgcn_rcpf(cs + 1e-8f);
    }
    hres_g[(size_t)(rowbase * 16) + ln] = M;  // (rowbase+rr)*16 + jj, coalesced
  }

  // phase 2: x_agg, LN(+affine), bf16 store — one row at a time per wave
#pragma unroll
  for (int r = 0; r < 4; ++r) {
    const int b = rowbase + r;
    const float* xb = xs + (size_t)b * SD;
    const float h0 = hpre[r][0], h1 = hpre[r][1], h2 = hpre[r][2], h3 = hpre[r][3];
    float4 agg[4];
    float asum = 0.f, asq = 0.f;
#pragma unroll
    for (int i2 = 0; i2 < 4; ++i2) {
      const int d = i2 * 256 + ln * 4;
      float4 g0 = *(const float4*)(xb + d);
      float4 g1 = *(const float4*)(xb + D + d);
      float4 g2 = *(const float4*)(xb + 2 * D + d);
      float4 g3 = *(const float4*)(xb + 3 * D + d);
      float4 a;
      a.x = h0 * g0.x + h1 * g1.x + h2 * g2.x + h3 * g3.x;
      a.y = h0 * g0.y + h1 * g1.y + h2 * g2.y + h3 * g3.y;
      a.z = h0 * g0.z + h1 * g1.z + h2 * g2.z + h3 * g3.z;
      a.w = h0 * g0.w + h1 * g1.w + h2 * g2.w + h3 * g3.w;
      agg[i2] = a;
      asum += a.x + a.y + a.z + a.w;
      asq += a.x * a.x + a.y * a.y + a.z * a.z + a.w * a.w;
    }
    asum = wred(asum);
    asq = wred(asq);
    const float mu2 = asum * (1.0f / 1024.0f);
    const float rstd2 = rsqrtf(asq * (1.0f / 1024.0f) - mu2 * mu2 + 1e-5f);
#pragma unroll
    for (int i2 = 0; i2 < 4; ++i2) {
      const int d = i2 * 256 + ln * 4;
      float4 g = *(const float4*)(gamma + d);
      float4 bb = *(const float4*)(beta + d);
      ushort4 u;
      u.x = f2bf((agg[i2].x - mu2) * rstd2 * g.x + bb.x);
      u.y = f2bf((agg[i2].y - mu2) * rstd2 * g.y + bb.y);
      u.z = f2bf((agg[i2].z - mu2) * rstd2 * g.z + bb.z);
      u.w = f2bf((agg[i2].w - mu2) * rstd2 * g.w + bb.w);
      *(ushort4*)(lnagg + (size_t)b * D + d) = u;
    }
  }
}

// ---------------- K2: bf16 MFMA GEMM out = lnagg @ W_layer^T + b_layer,
// fused epilogue: updated[b,s,:] = sum_t hres[s,t]*x[b,t,:] + out*hpost[s],
// mean = avg_s updated. Tiles 128x128, BK=64, LDS rows padded to 72 bf16.
__global__ __launch_bounds__(256) void k2_gemm_ep(
    const unsigned short* __restrict__ A,   // lnagg bf16 [8192][1024]
    const unsigned short* __restrict__ Bw,  // W_layer bf16 [1024][1024]
    const float* __restrict__ blayer,
    const float* __restrict__ xs,
    const float* __restrict__ hres_g, const float* __restrict__ hpost_g,
    float* __restrict__ outMean, float* __restrict__ outUpd) {
  __shared__ uint4 As4[128 * 9];  // 128 rows x 72 bf16 (9 uint4)
  __shared__ uint4 Bs4[128 * 9];
  __shared__ float HR[128 * 17];
  __shared__ float HP[128 * 5];

  const int tid = threadIdx.x;
  const int l = tid & 63;
  const int wv = tid >> 6;
  const int wm = wv >> 1, wn = wv & 1;
  const int lrow = l & 15, lq = l >> 4;
  const int bm0 = blockIdx.x * 128;
  const int bn0 = blockIdx.y * 128;

#pragma unroll
  for (int i = 0; i < 8; ++i) {
    int idx = i * 256 + tid;  // 0..2047
    HR[(idx >> 4) * 17 + (idx & 15)] = hres_g[(size_t)bm0 * 16 + idx];
  }
#pragma unroll
  for (int i = 0; i < 2; ++i) {
    int idx = i * 256 + tid;  // 0..511
    HP[(idx >> 2) * 5 + (idx & 3)] = hpost_g[(size_t)bm0 * 4 + idx];
  }

  f32x4 acc[4][4] = {};

#pragma unroll 1
  for (int kt = 0; kt < 16; ++kt) {
    __syncthreads();
#pragma unroll
    for (int i = 0; i < 4; ++i) {
      const int c = i * 256 + tid;  // 0..1023 16B-chunks
      const int row = c >> 3, cc = c & 7;
      As4[row * 9 + cc] = *(const uint4*)(A + (size_t)(bm0 + row) * 1024 + kt * 64 + cc * 8);
      Bs4[row * 9 + cc] = *(const uint4*)(Bw + (size_t)(bn0 + row) * 1024 + kt * 64 + cc * 8);
    }
    __syncthreads();
#pragma unroll
    for (int kk = 0; kk < 2; ++kk) {
      bf16x8 af[4], bfr[4];
#pragma unroll
      for (int t = 0; t < 4; ++t) {
        af[t] = *(const bf16x8*)(As4 + (wm * 64 + t * 16 + lrow) * 9 + kk * 4 + lq);
        bfr[t] = *(const bf16x8*)(Bs4 + (wn * 64 + t * 16 + lrow) * 9 + kk * 4 + lq);
      }
#pragma unroll
      for (int ti = 0; ti < 4; ++ti)
#pragma unroll
        for (int tj = 0; tj < 4; ++tj)
          acc[ti][tj] =
              __builtin_amdgcn_mfma_f32_16x16x32_bf16(af[ti], bfr[tj], acc[ti][tj], 0, 0, 0);
    }
  }

  // epilogue — C/D layout: row=(l>>4)*4+reg, col=l&15 (m89-verified)
#pragma unroll
  for (int ti = 0; ti < 4; ++ti) {
#pragma unroll
    for (int r2 = 0; r2 < 4; ++r2) {
      const int bl = wm * 64 + ti * 16 + lq * 4 + r2;
      const int b = bm0 + bl;
      float hr[16], hp[4];
#pragma unroll
      for (int q = 0; q < 16; ++q) hr[q] = HR[bl * 17 + q];
#pragma unroll
      for (int q = 0; q < 4; ++q) hp[q] = HP[bl * 5 + q];
      const float c0 = 0.25f * (hr[0] + hr[4] + hr[8] + hr[12]);
      const float c1 = 0.25f * (hr[1] + hr[5] + hr[9] + hr[13]);
      const float c2 = 0.25f * (hr[2] + hr[6] + hr[10] + hr[14]);
      const float c3 = 0.25f * (hr[3] + hr[7] + hr[11] + hr[15]);
      const float hps = 0.25f * (hp[0] + hp[1] + hp[2] + hp[3]);
      const float* xb = xs + (size_t)b * SD;
#pragma unroll
      for (int tj = 0; tj < 4; ++tj) {
        const int d = bn0 + wn * 64 + tj * 16 + lrow;
        const float ov = acc[ti][tj][r2] + blayer[d];
        const float x0 = xb[d], x1 = xb[1024 + d], x2 = xb[2048 + d], x3 = xb[3072 + d];
        outMean[(size_t)b * 1024 + d] = c0 * x0 + c1 * x1 + c2 * x2 + c3 * x3 + ov * hps;
        float* up = outUpd + (size_t)b * 4096 + d;
        up[0] = hr[0] * x0 + hr[1] * x1 + hr[2] * x2 + hr[3] * x3 + ov * hp[0];
        up[1024] = hr[4] * x0 + hr[5] * x1 + hr[6] * x2 + hr[7] * x3 + ov * hp[1];
        up[2048] = hr[8] * x0 + hr[9] * x1 + hr[10] * x2 + hr[11] * x3 + ov * hp[2];
        up[3072] = hr[12] * x0 + hr[13] * x1 + hr[14] * x2 + hr[15] * x3 + ov * hp[3];
      }
    }
  }
}

// ---------------- launch ----------------
extern "C" void kernel_launch(void* const* d_in, const int* in_sizes, int n_in,
                              void* d_out, int out_size, void* d_ws, size_t ws_size,
                              hipStream_t stream) {
  const float* xs = (const float*)d_in[1];
  const float* Wpre = (const float*)d_in[2];
  const float* bpre = (const float*)d_in[3];
  const float* Wpost = (const float*)d_in[4];
  const float* bpost = (const float*)d_in[5];
  const float* Wres = (const float*)d_in[6];
  const float* bres = (const float*)d_in[7];
  const float* apre = (const float*)d_in[8];
  const float* apost = (const float*)d_in[9];
  const float* ares = (const float*)d_in[10];
  const float* gamma = (const float*)d_in[11];
  const float* beta = (const float*)d_in[12];
  const float* Wlayer = (const float*)d_in[13];
  const float* blayer = (const float*)d_in[14];

  // workspace layout (bytes): [0,2MB) W_layer bf16 | [2MB,18MB) lnagg bf16
  // | hres 512KB | hpost 128KB | wsum 96B
  const size_t OFF_LNAGG = (size_t)2 << 20;
  const size_t OFF_HRES = (size_t)18 << 20;
  const size_t OFF_HPOST = OFF_HRES + (size_t)BROWS * 16 * 4;
  const size_t OFF_WSUM = OFF_HPOST + (size_t)BROWS * 4 * 4;
  if (ws_size < OFF_WSUM + 128) return;  // workspace too small — fail visibly

  char* ws = (char*)d_ws;
  unsigned short* wl16 = (unsigned short*)ws;
  unsigned short* lnagg = (unsigned short*)(ws + OFF_LNAGG);
  float* hresb = (float*)(ws + OFF_HRES);
  float* hpostb = (float*)(ws + OFF_HPOST);
  float* wsum = (float*)(ws + OFF_WSUM);

  float* outMean = (float*)d_out;
  float* outUpd = outMean + (size_t)BROWS * D;

  hipLaunchKernelGGL(k0_wsum, dim3(24), dim3(256), 0, stream, Wpre, Wpost, Wres, wsum);
  hipLaunchKernelGGL(k0_conv, dim3(1024), dim3(256), 0, stream, Wlayer, wl16);
  hipLaunchKernelGGL(k1_rowpass, dim3(512), dim3(256), 0, stream, xs, Wpre, bpre, Wpost,
                     bpost, Wres, bres, apre, apost, ares, gamma, beta, wsum, lnagg, hresb,
                     hpostb);
  hipLaunchKernelGGL(k2_gemm_ep, dim3(64, 8), dim3(256), 0, stream, lnagg, wl16, blayer, xs,
                     hresb, hpostb, outMean, outUpd);
}

// Round 2
// 408.598 us; speedup vs baseline: 1.2171x; 1.2171x over previous
//
#include <hip/hip_runtime.h>

#define DEV __device__ __forceinline__

typedef __bf16 bf16x8 __attribute__((ext_vector_type(8)));
typedef float f32x4 __attribute__((ext_vector_type(4)));
typedef unsigned int u32;

constexpr int BROWS = 8192;
constexpr int D = 1024;
constexpr int SD = 4096;

// ---------------- helpers ----------------
DEV unsigned short f2bf(float f) {  // RNE float->bf16
  unsigned int u = __float_as_uint(f);
  u = (u + 0x7FFFu + ((u >> 16) & 1u)) >> 16;
  return (unsigned short)u;
}

DEV float wred(float v) {  // full 64-lane butterfly sum (result in all lanes)
#pragma unroll
  for (int m = 1; m < 64; m <<= 1) v += __shfl_xor(v, m);
  return v;
}

DEV float sigmoidf(float x) { return 1.0f / (1.0f + __expf(-x)); }

DEV void async_ld16(const void* g, void* l) {  // 16B global -> LDS DMA
  __builtin_amdgcn_global_load_lds((const __attribute__((address_space(1))) u32*)g,
                                   (__attribute__((address_space(3))) u32*)l, 16, 0, 0);
}

// ---------------- K0a: row-sums of the 24 gate weight rows ----------------
__global__ __launch_bounds__(256) void k0_wsum(
    const float* __restrict__ Wpre, const float* __restrict__ Wpost,
    const float* __restrict__ Wres, float* __restrict__ wsum) {
  const int j = blockIdx.x;  // 0..23: 0-3 pre, 4-7 post, 8-23 res
  const float* src = (j < 4) ? (Wpre + j * SD)
                             : (j < 8 ? (Wpost + (j - 4) * SD) : (Wres + (j - 8) * SD));
  float s = 0.f;
  for (int i = threadIdx.x * 4; i < SD; i += 1024) {
    float4 v = *(const float4*)(src + i);
    s += v.x + v.y + v.z + v.w;
  }
  s = wred(s);
  __shared__ float tmp[4];
  if ((threadIdx.x & 63) == 0) tmp[threadIdx.x >> 6] = s;
  __syncthreads();
  if (threadIdx.x == 0) wsum[j] = tmp[0] + tmp[1] + tmp[2] + tmp[3];
}

// ---------------- K0b: W_layer fp32 -> bf16 ----------------
__global__ __launch_bounds__(256) void k0_conv(const float* __restrict__ W,
                                               unsigned short* __restrict__ out) {
  const int i = (blockIdx.x * 256 + threadIdx.x) * 4;
  float4 v = *(const float4*)(W + i);
  ushort4 u;
  u.x = f2bf(v.x); u.y = f2bf(v.y); u.z = f2bf(v.z); u.w = f2bf(v.w);
  *(ushort4*)(out + i) = u;
}

// ---------------- K1: fused per-row pass ----------------
// 2048 blocks x 256. Block = 4 rows. Wave w computes dots j in [6w,6w+6) for
// all 4 rows (24 acc) + stats for all 4 rows (redundant across waves -> no
// stats exchange). Raw dots -> LDS; wave0 sinkhorn, wave1 hpre/hpost; then
// per-wave x_agg + LN -> bf16 lnagg.
__global__ __launch_bounds__(256) void k1_rowpass(
    const float* __restrict__ xs,
    const float* __restrict__ Wpre, const float* __restrict__ bpre,
    const float* __restrict__ Wpost, const float* __restrict__ bpost,
    const float* __restrict__ Wres, const float* __restrict__ bres,
    const float* __restrict__ s_apre, const float* __restrict__ s_apost,
    const float* __restrict__ s_ares,
    const float* __restrict__ gamma, const float* __restrict__ beta,
    const float* __restrict__ wsum,
    unsigned short* __restrict__ lnagg,
    float* __restrict__ hres_g, float* __restrict__ hpost_g) {
  const int tid = threadIdx.x;
  const int wv = tid >> 6;
  const int ln = tid & 63;
  const int rb = blockIdx.x * 4;

  __shared__ float DOT[24][4];
  __shared__ float HPRE[4][4];

  const int jb = wv * 6;
  const float* Wj[6];
#pragma unroll
  for (int q = 0; q < 6; ++q) {
    const int j = jb + q;
    Wj[q] = (j < 4) ? (Wpre + j * SD) : (j < 8) ? (Wpost + (j - 4) * SD) : (Wres + (j - 8) * SD);
  }
  const float* xr0 = xs + (size_t)(rb + 0) * SD;
  const float* xr1 = xs + (size_t)(rb + 1) * SD;
  const float* xr2 = xs + (size_t)(rb + 2) * SD;
  const float* xr3 = xs + (size_t)(rb + 3) * SD;

  float acc6[6][4];
#pragma unroll
  for (int q = 0; q < 6; ++q)
#pragma unroll
    for (int r = 0; r < 4; ++r) acc6[q][r] = 0.f;
  float sum4[4] = {0.f, 0.f, 0.f, 0.f}, sq4[4] = {0.f, 0.f, 0.f, 0.f};

#pragma unroll 1
  for (int it = 0; it < 16; ++it) {
    const int i = it * 256 + ln * 4;
    float4 xv[4];
    xv[0] = *(const float4*)(xr0 + i);
    xv[1] = *(const float4*)(xr1 + i);
    xv[2] = *(const float4*)(xr2 + i);
    xv[3] = *(const float4*)(xr3 + i);
#pragma unroll
    for (int r = 0; r < 4; ++r) {
      sum4[r] += xv[r].x + xv[r].y + xv[r].z + xv[r].w;
      sq4[r] += xv[r].x * xv[r].x + xv[r].y * xv[r].y + xv[r].z * xv[r].z + xv[r].w * xv[r].w;
    }
#pragma unroll
    for (int q = 0; q < 6; ++q) {
      const float4 w = *(const float4*)(Wj[q] + i);
#pragma unroll
      for (int r = 0; r < 4; ++r)
        acc6[q][r] += w.x * xv[r].x + w.y * xv[r].y + w.z * xv[r].z + w.w * xv[r].w;
    }
  }

#pragma unroll
  for (int q = 0; q < 6; ++q)
#pragma unroll
    for (int r = 0; r < 4; ++r) acc6[q][r] = wred(acc6[q][r]);
#pragma unroll
  for (int r = 0; r < 4; ++r) { sum4[r] = wred(sum4[r]); sq4[r] = wred(sq4[r]); }

  float mu4[4], rs4[4];
#pragma unroll
  for (int r = 0; r < 4; ++r) {
    mu4[r] = sum4[r] * (1.0f / 4096.0f);
    rs4[r] = rsqrtf(sq4[r] * (1.0f / 4096.0f) - mu4[r] * mu4[r] + 1e-5f);
  }

  if (ln == 0) {
#pragma unroll
    for (int q = 0; q < 6; ++q)
#pragma unroll
      for (int r = 0; r < 4; ++r) DOT[jb + q][r] = acc6[q][r];
  }
  __syncthreads();

  if (wv == 0) {  // sinkhorn: 64 lanes = 4 rows x 16 entries
    const float ares = s_ares[0];
    const int rr = ln >> 4, jj = ln & 15;
    const float corr = rs4[rr] * (DOT[8 + jj][rr] - mu4[rr] * wsum[8 + jj]);
    float M = __expf(ares * (corr + bres[jj]));
#pragma unroll 1
    for (int itr = 0; itr < 20; ++itr) {
      float rs = M + __shfl_xor(M, 1);
      rs += __shfl_xor(rs, 2);
      M *= __builtin_amdgcn_rcpf(rs + 1e-8f);
      float cs = M + __shfl_xor(M, 4);
      cs += __shfl_xor(cs, 8);
      M *= __builtin_amdgcn_rcpf(cs + 1e-8f);
    }
    hres_g[(size_t)rb * 16 + ln] = M;
  } else if (wv == 1) {
    if (ln < 16) {
      const int r = ln >> 2, s = ln & 3;
      const float corr = rs4[r] * (DOT[s][r] - mu4[r] * wsum[s]);
      HPRE[r][s] = sigmoidf(s_apre[0] * (corr + bpre[s]));
    } else if (ln < 32) {
      const int idx = ln - 16, r = idx >> 2, s = idx & 3;
      const float corr = rs4[r] * (DOT[4 + s][r] - mu4[r] * wsum[4 + s]);
      hpost_g[(rb + r) * 4 + s] = 2.0f * sigmoidf(s_apost[0] * (corr + bpost[s]));
    }
  }
  __syncthreads();

  // phase 2: x_agg + LN + bf16 store — wave w owns row rb+w (x re-read = L2 hit)
  {
    const int b = rb + wv;
    const float* xb = xs + (size_t)b * SD;
    const float h0 = HPRE[wv][0], h1 = HPRE[wv][1], h2 = HPRE[wv][2], h3 = HPRE[wv][3];
    float4 agg[4];
    float asum = 0.f, asq = 0.f;
#pragma unroll
    for (int i2 = 0; i2 < 4; ++i2) {
      const int d = i2 * 256 + ln * 4;
      float4 g0 = *(const float4*)(xb + d);
      float4 g1 = *(const float4*)(xb + D + d);
      float4 g2 = *(const float4*)(xb + 2 * D + d);
      float4 g3 = *(const float4*)(xb + 3 * D + d);
      float4 a;
      a.x = h0 * g0.x + h1 * g1.x + h2 * g2.x + h3 * g3.x;
      a.y = h0 * g0.y + h1 * g1.y + h2 * g2.y + h3 * g3.y;
      a.z = h0 * g0.z + h1 * g1.z + h2 * g2.z + h3 * g3.z;
      a.w = h0 * g0.w + h1 * g1.w + h2 * g2.w + h3 * g3.w;
      agg[i2] = a;
      asum += a.x + a.y + a.z + a.w;
      asq += a.x * a.x + a.y * a.y + a.z * a.z + a.w * a.w;
    }
    asum = wred(asum);
    asq = wred(asq);
    const float mu2 = asum * (1.0f / 1024.0f);
    const float rstd2 = rsqrtf(asq * (1.0f / 1024.0f) - mu2 * mu2 + 1e-5f);
#pragma unroll
    for (int i2 = 0; i2 < 4; ++i2) {
      const int d = i2 * 256 + ln * 4;
      float4 g = *(const float4*)(gamma + d);
      float4 bb = *(const float4*)(beta + d);
      ushort4 u;
      u.x = f2bf((agg[i2].x - mu2) * rstd2 * g.x + bb.x);
      u.y = f2bf((agg[i2].y - mu2) * rstd2 * g.y + bb.y);
      u.z = f2bf((agg[i2].z - mu2) * rstd2 * g.z + bb.z);
      u.w = f2bf((agg[i2].w - mu2) * rstd2 * g.w + bb.w);
      *(ushort4*)(lnagg + (size_t)b * D + d) = u;
    }
  }
}

// ---------------- K2: bf16 MFMA GEMM + fused epilogue ----------------
// out = lnagg @ W_layer^T + b_layer; updated[b,s,:] = sum_t hres[s,t]*x[b,t,:]
// + out*hpost[s]; mean = avg_s updated. 128x128 tile, BK=64.
// Staging: global_load_lds dwordx4 into XOR-swizzled linear LDS (swizzle on
// the GLOBAL chunk index keeps lane->LDS mapping linear). Epilogue: acc ->
// LDS (32x132 fp32) -> vectorized float4 streaming per 32-row chunk.
__global__ __launch_bounds__(256) void k2_gemm_ep(
    const unsigned short* __restrict__ A,   // lnagg bf16 [8192][1024]
    const unsigned short* __restrict__ Bw,  // W_layer bf16 [1024][1024]
    const float* __restrict__ blayer,
    const float* __restrict__ xs,
    const float* __restrict__ hres_g, const float* __restrict__ hpost_g,
    float* __restrict__ outMean, float* __restrict__ outUpd) {
  __shared__ char smem[44032];
  char* AsB = smem;            // 16384 B: 128 rows x 64 bf16 (8 chunks of 16B)
  char* BsB = smem + 16384;    // 16384 B
  float* EP = (float*)smem;    // epilogue overlay: 32 x 132 fp32 = 16896 B
  float* HR = (float*)(smem + 32768);  // 128 x 17
  float* HP = (float*)(smem + 41472);  // 128 x 5

  const int tid = threadIdx.x;
  const int l = tid & 63;
  const int wv = tid >> 6;
  const int wm = wv >> 1, wn = wv & 1;
  const int lrow = l & 15, lq = l >> 4;
  const int bm0 = blockIdx.x * 128;
  const int bn0 = blockIdx.y * 128;

#pragma unroll
  for (int i = 0; i < 8; ++i) {
    int idx = i * 256 + tid;  // 0..2047
    HR[(idx >> 4) * 17 + (idx & 15)] = hres_g[(size_t)bm0 * 16 + idx];
  }
#pragma unroll
  for (int i = 0; i < 2; ++i) {
    int idx = i * 256 + tid;  // 0..511
    HP[(idx >> 2) * 5 + (idx & 3)] = hpost_g[(size_t)bm0 * 4 + idx];
  }

  f32x4 acc[4][4] = {};

#pragma unroll 1
  for (int kt = 0; kt < 16; ++kt) {
    __syncthreads();  // previous iter's frag reads done before overwrite
#pragma unroll
    for (int c = 0; c < 4; ++c) {
      const int idx = c * 256 + tid;              // 16B-chunk index 0..1023
      const int row = idx >> 3, cc = idx & 7;
      const int gch = cc ^ (row & 7);             // XOR swizzle on global side
      async_ld16((const char*)A + ((size_t)(bm0 + row) << 11) + kt * 128 + gch * 16,
                 AsB + idx * 16);
      async_ld16((const char*)Bw + ((size_t)(bn0 + row) << 11) + kt * 128 + gch * 16,
                 BsB + idx * 16);
    }
    __syncthreads();  // staged data visible (vmcnt(0) drained by barrier)
#pragma unroll
    for (int kk = 0; kk < 2; ++kk) {
      bf16x8 af[4], bfr[4];
      const int sw = (kk * 4 + lq);
#pragma unroll
      for (int t = 0; t < 4; ++t) {
        const int ra = wm * 64 + t * 16 + lrow;
        const int rbr = wn * 64 + t * 16 + lrow;
        af[t] = *(const bf16x8*)(AsB + ra * 128 + (sw ^ (ra & 7)) * 16);
        bfr[t] = *(const bf16x8*)(BsB + rbr * 128 + (sw ^ (rbr & 7)) * 16);
      }
#pragma unroll
      for (int ti = 0; ti < 4; ++ti)
#pragma unroll
        for (int tj = 0; tj < 4; ++tj)
          acc[ti][tj] =
              __builtin_amdgcn_mfma_f32_16x16x32_bf16(af[ti], bfr[tj], acc[ti][tj], 0, 0, 0);
    }
  }

  // ---- epilogue: 4 chunks of 32 rows; LDS transpose then vectorized stream
  // C/D layout: row_local = wm*64 + ti*16 + lq*4 + r2, col_local = wn*64 + tj*16 + lrow
#pragma unroll
  for (int ti = 0; ti < 4; ++ti) {
    __syncthreads();  // protect As/Bs (kt loop) or previous EP chunk readers
#pragma unroll
    for (int tj = 0; tj < 4; ++tj)
#pragma unroll
      for (int r2 = 0; r2 < 4; ++r2)
        EP[(wm * 16 + lq * 4 + r2) * 132 + wn * 64 + tj * 16 + lrow] = acc[ti][tj][r2];
    __syncthreads();

    const int rr2 = tid >> 3;        // 0..31
    const int c0 = (tid & 7) * 4;    // first float4 col, stride 32 over k2i
    const int bl = (rr2 >> 4) * 64 + ti * 16 + (rr2 & 15);
    const int gr = bm0 + bl;
    float hr[16], hp4[4];
#pragma unroll
    for (int q = 0; q < 16; ++q) hr[q] = HR[bl * 17 + q];
#pragma unroll
    for (int q = 0; q < 4; ++q) hp4[q] = HP[bl * 5 + q];
    const float cm0 = 0.25f * (hr[0] + hr[4] + hr[8] + hr[12]);
    const float cm1 = 0.25f * (hr[1] + hr[5] + hr[9] + hr[13]);
    const float cm2 = 0.25f * (hr[2] + hr[6] + hr[10] + hr[14]);
    const float cm3 = 0.25f * (hr[3] + hr[7] + hr[11] + hr[15]);
    const float hps = 0.25f * (hp4[0] + hp4[1] + hp4[2] + hp4[3]);
    const float* xb = xs + (size_t)gr * SD + bn0;
    float* um = outMean + (size_t)gr * 1024 + bn0;
    float* uu = outUpd + (size_t)gr * 4096 + bn0;
#pragma unroll
    for (int k2i = 0; k2i < 4; ++k2i) {
      const int col = c0 + k2i * 32;
      f32x4 ov = *(const f32x4*)(EP + rr2 * 132 + col);
      ov += *(const f32x4*)(blayer + bn0 + col);
      const f32x4 x0 = *(const f32x4*)(xb + col);
      const f32x4 x1 = *(const f32x4*)(xb + 1024 + col);
      const f32x4 x2 = *(const f32x4*)(xb + 2048 + col);
      const f32x4 x3 = *(const f32x4*)(xb + 3072 + col);
      *(f32x4*)(um + col) = cm0 * x0 + cm1 * x1 + cm2 * x2 + cm3 * x3 + ov * hps;
      *(f32x4*)(uu + col) = hr[0] * x0 + hr[1] * x1 + hr[2] * x2 + hr[3] * x3 + ov * hp4[0];
      *(f32x4*)(uu + 1024 + col) = hr[4] * x0 + hr[5] * x1 + hr[6] * x2 + hr[7] * x3 + ov * hp4[1];
      *(f32x4*)(uu + 2048 + col) = hr[8] * x0 + hr[9] * x1 + hr[10] * x2 + hr[11] * x3 + ov * hp4[2];
      *(f32x4*)(uu + 3072 + col) = hr[12] * x0 + hr[13] * x1 + hr[14] * x2 + hr[15] * x3 + ov * hp4[3];
    }
  }
}

// ---------------- launch ----------------
extern "C" void kernel_launch(void* const* d_in, const int* in_sizes, int n_in,
                              void* d_out, int out_size, void* d_ws, size_t ws_size,
                              hipStream_t stream) {
  const float* xs = (const float*)d_in[1];
  const float* Wpre = (const float*)d_in[2];
  const float* bpre = (const float*)d_in[3];
  const float* Wpost = (const float*)d_in[4];
  const float* bpost = (const float*)d_in[5];
  const float* Wres = (const float*)d_in[6];
  const float* bres = (const float*)d_in[7];
  const float* apre = (const float*)d_in[8];
  const float* apost = (const float*)d_in[9];
  const float* ares = (const float*)d_in[10];
  const float* gamma = (const float*)d_in[11];
  const float* beta = (const float*)d_in[12];
  const float* Wlayer = (const float*)d_in[13];
  const float* blayer = (const float*)d_in[14];

  const size_t OFF_LNAGG = (size_t)2 << 20;
  const size_t OFF_HRES = (size_t)18 << 20;
  const size_t OFF_HPOST = OFF_HRES + (size_t)BROWS * 16 * 4;
  const size_t OFF_WSUM = OFF_HPOST + (size_t)BROWS * 4 * 4;
  if (ws_size < OFF_WSUM + 128) return;

  char* ws = (char*)d_ws;
  unsigned short* wl16 = (unsigned short*)ws;
  unsigned short* lnagg = (unsigned short*)(ws + OFF_LNAGG);
  float* hresb = (float*)(ws + OFF_HRES);
  float* hpostb = (float*)(ws + OFF_HPOST);
  float* wsum = (float*)(ws + OFF_WSUM);

  float* outMean = (float*)d_out;
  float* outUpd = outMean + (size_t)BROWS * D;

  hipLaunchKernelGGL(k0_wsum, dim3(24), dim3(256), 0, stream, Wpre, Wpost, Wres, wsum);
  hipLaunchKernelGGL(k0_conv, dim3(1024), dim3(256), 0, stream, Wlayer, wl16);
  hipLaunchKernelGGL(k1_rowpass, dim3(2048), dim3(256), 0, stream, xs, Wpre, bpre, Wpost,
                     bpost, Wres, bres, apre, apost, ares, gamma, beta, wsum, lnagg, hresb,
                     hpostb);
  hipLaunchKernelGGL(k2_gemm_ep, dim3(64, 8), dim3(256), 0, stream, lnagg, wl16, blayer, xs,
                     hresb, hpostb, outMean, outUpd);
}

// Round 3
// 396.187 us; speedup vs baseline: 1.2552x; 1.0313x over previous
//
#include <hip/hip_runtime.h>

#define DEV __device__ __forceinline__

typedef __bf16 bf16x8 __attribute__((ext_vector_type(8)));
typedef float f32x4 __attribute__((ext_vector_type(4)));
typedef unsigned int u32;

constexpr int BROWS = 8192;
constexpr int D = 1024;
constexpr int SD = 4096;

// ---------------- helpers ----------------
DEV unsigned short f2bf(float f) {  // RNE float->bf16
  unsigned int u = __float_as_uint(f);
  u = (u + 0x7FFFu + ((u >> 16) & 1u)) >> 16;
  return (unsigned short)u;
}

DEV float wred(float v) {  // full 64-lane butterfly sum (result in all lanes)
#pragma unroll
  for (int m = 1; m < 64; m <<= 1) v += __shfl_xor(v, m);
  return v;
}

DEV float sigmoidf(float x) { return 1.0f / (1.0f + __expf(-x)); }

DEV void async_ld16(const void* g, void* l) {  // 16B global -> LDS DMA
  __builtin_amdgcn_global_load_lds((const __attribute__((address_space(1))) u32*)g,
                                   (__attribute__((address_space(3))) u32*)l, 16, 0, 0);
}

// ---------------- K0: prep — W_layer->bf16, pack 24 gate rows, row-sums ----
__global__ __launch_bounds__(256) void k0_prep(
    const float* __restrict__ Wlayer, const float* __restrict__ Wpre,
    const float* __restrict__ Wpost, const float* __restrict__ Wres,
    unsigned short* __restrict__ wl16, float* __restrict__ Wall,
    float* __restrict__ wsum) {
  const int bx = blockIdx.x, tid = threadIdx.x;
  if (bx < 1024) {  // W_layer fp32 -> bf16
    const int i = bx * 1024 + tid * 4;
    float4 v = *(const float4*)(Wlayer + i);
    ushort4 u = make_ushort4(f2bf(v.x), f2bf(v.y), f2bf(v.z), f2bf(v.w));
    *(ushort4*)(wl16 + i) = u;
  } else {  // pack gate row j into Wall + row-sum
    const int j = bx - 1024;  // 0..23
    const float* src = (j < 4) ? (Wpre + j * SD)
                               : (j < 8 ? (Wpost + (j - 4) * SD) : (Wres + (j - 8) * SD));
    float s = 0.f;
    for (int i = tid * 4; i < SD; i += 1024) {
      float4 v = *(const float4*)(src + i);
      *(float4*)(Wall + j * SD + i) = v;
      s += v.x + v.y + v.z + v.w;
    }
    s = wred(s);
    __shared__ float tmp[4];
    if ((tid & 63) == 0) tmp[tid >> 6] = s;
    __syncthreads();
    if (tid == 0) wsum[j] = tmp[0] + tmp[1] + tmp[2] + tmp[3];
  }
}

// ---------------- K1: fused per-row pass, software-pipelined ----------------
// Block = 4 rows. Wave w computes dots j in [6w,6w+6) for all 4 rows (24 acc)
// + stats for all 4 rows (redundant, no exchange). Depth-1 register double
// buffer: prefetch iter k+1's 10 float4s while FMA-ing iter k.
__global__ __launch_bounds__(256) void k1_rowpass(
    const float* __restrict__ xs, const float* __restrict__ Wall,
    const float* __restrict__ bpre, const float* __restrict__ bpost,
    const float* __restrict__ bres,
    const float* __restrict__ s_apre, const float* __restrict__ s_apost,
    const float* __restrict__ s_ares,
    const float* __restrict__ gamma, const float* __restrict__ beta,
    const float* __restrict__ wsum,
    unsigned short* __restrict__ lnagg,
    float* __restrict__ hres_g, float* __restrict__ hpost_g) {
  const int tid = threadIdx.x;
  const int wv = tid >> 6;
  const int ln = tid & 63;
  const int rb = blockIdx.x * 4;

  __shared__ float DOT[24][4];
  __shared__ float HPRE[4][4];

  const int jb = wv * 6;
  const float* Wb = Wall + (size_t)jb * SD;
  const float* xb0 = xs + (size_t)rb * SD;
  const int l4 = ln * 4;

  float acc6[6][4];
#pragma unroll
  for (int q = 0; q < 6; ++q)
#pragma unroll
    for (int r = 0; r < 4; ++r) acc6[q][r] = 0.f;
  float sum4[4] = {0.f, 0.f, 0.f, 0.f}, sq4[4] = {0.f, 0.f, 0.f, 0.f};

  float4 xA[4], wA[6], xB[4], wB[6];

#define LDX(dst, it)                                      \
  {                                                       \
    const int i_ = (it)*256 + l4;                         \
    dst[0] = *(const float4*)(xb0 + i_);                  \
    dst[1] = *(const float4*)(xb0 + SD + i_);             \
    dst[2] = *(const float4*)(xb0 + 2 * SD + i_);         \
    dst[3] = *(const float4*)(xb0 + 3 * SD + i_);         \
  }
#define LDW(dst, it)                                      \
  {                                                       \
    const int i_ = (it)*256 + l4;                         \
    _Pragma("unroll") for (int q = 0; q < 6; ++q)         \
        dst[q] = *(const float4*)(Wb + q * SD + i_);      \
  }
#define CMP(X, W)                                                              \
  {                                                                            \
    _Pragma("unroll") for (int r = 0; r < 4; ++r) {                            \
      sum4[r] += X[r].x + X[r].y + X[r].z + X[r].w;                            \
      sq4[r] += X[r].x * X[r].x + X[r].y * X[r].y + X[r].z * X[r].z +          \
                X[r].w * X[r].w;                                               \
    }                                                                          \
    _Pragma("unroll") for (int q = 0; q < 6; ++q) {                            \
      _Pragma("unroll") for (int r = 0; r < 4; ++r) acc6[q][r] +=              \
          W[q].x * X[r].x + W[q].y * X[r].y + W[q].z * X[r].z + W[q].w * X[r].w;\
    }                                                                          \
  }

  LDX(xA, 0);
  LDW(wA, 0);
#pragma unroll 1
  for (int it = 0; it < 16; it += 2) {
    LDX(xB, it + 1);
    LDW(wB, it + 1);
    CMP(xA, wA);  // waits vmcnt(10): B-buffer stays in flight
    if (it < 14) {
      LDX(xA, it + 2);
      LDW(wA, it + 2);
    }
    CMP(xB, wB);
  }
#undef LDX
#undef LDW
#undef CMP

#pragma unroll
  for (int q = 0; q < 6; ++q)
#pragma unroll
    for (int r = 0; r < 4; ++r) acc6[q][r] = wred(acc6[q][r]);
#pragma unroll
  for (int r = 0; r < 4; ++r) { sum4[r] = wred(sum4[r]); sq4[r] = wred(sq4[r]); }

  float mu4[4], rs4[4];
#pragma unroll
  for (int r = 0; r < 4; ++r) {
    mu4[r] = sum4[r] * (1.0f / 4096.0f);
    rs4[r] = rsqrtf(sq4[r] * (1.0f / 4096.0f) - mu4[r] * mu4[r] + 1e-5f);
  }

  if (ln == 0) {
#pragma unroll
    for (int q = 0; q < 6; ++q)
#pragma unroll
      for (int r = 0; r < 4; ++r) DOT[jb + q][r] = acc6[q][r];
  }
  __syncthreads();

  if (wv == 0) {  // sinkhorn: 64 lanes = 4 rows x 16 entries
    const float ares = s_ares[0];
    const int rr = ln >> 4, jj = ln & 15;
    const float corr = rs4[rr] * (DOT[8 + jj][rr] - mu4[rr] * wsum[8 + jj]);
    float M = __expf(ares * (corr + bres[jj]));
#pragma unroll 1
    for (int itr = 0; itr < 20; ++itr) {
      float rs = M + __shfl_xor(M, 1);
      rs += __shfl_xor(rs, 2);
      M *= __builtin_amdgcn_rcpf(rs + 1e-8f);
      float cs = M + __shfl_xor(M, 4);
      cs += __shfl_xor(cs, 8);
      M *= __builtin_amdgcn_rcpf(cs + 1e-8f);
    }
    hres_g[(size_t)rb * 16 + ln] = M;
  } else if (wv == 1) {
    if (ln < 16) {
      const int r = ln >> 2, s = ln & 3;
      const float corr = rs4[r] * (DOT[s][r] - mu4[r] * wsum[s]);
      HPRE[r][s] = sigmoidf(s_apre[0] * (corr + bpre[s]));
    } else if (ln < 32) {
      const int idx = ln - 16, r = idx >> 2, s = idx & 3;
      const float corr = rs4[r] * (DOT[4 + s][r] - mu4[r] * wsum[4 + s]);
      hpost_g[(rb + r) * 4 + s] = 2.0f * sigmoidf(s_apost[0] * (corr + bpost[s]));
    }
  }
  __syncthreads();

  // phase 2: x_agg + LN + bf16 store — wave w owns row rb+w (x re-read = L2 hit)
  {
    const int b = rb + wv;
    const float* xb = xs + (size_t)b * SD;
    const float h0 = HPRE[wv][0], h1 = HPRE[wv][1], h2 = HPRE[wv][2], h3 = HPRE[wv][3];
    float4 agg[4];
    float asum = 0.f, asq = 0.f;
#pragma unroll
    for (int i2 = 0; i2 < 4; ++i2) {
      const int d = i2 * 256 + l4;
      float4 g0 = *(const float4*)(xb + d);
      float4 g1 = *(const float4*)(xb + D + d);
      float4 g2 = *(const float4*)(xb + 2 * D + d);
      float4 g3 = *(const float4*)(xb + 3 * D + d);
      float4 a;
      a.x = h0 * g0.x + h1 * g1.x + h2 * g2.x + h3 * g3.x;
      a.y = h0 * g0.y + h1 * g1.y + h2 * g2.y + h3 * g3.y;
      a.z = h0 * g0.z + h1 * g1.z + h2 * g2.z + h3 * g3.z;
      a.w = h0 * g0.w + h1 * g1.w + h2 * g2.w + h3 * g3.w;
      agg[i2] = a;
      asum += a.x + a.y + a.z + a.w;
      asq += a.x * a.x + a.y * a.y + a.z * a.z + a.w * a.w;
    }
    asum = wred(asum);
    asq = wred(asq);
    const float mu2 = asum * (1.0f / 1024.0f);
    const float rstd2 = rsqrtf(asq * (1.0f / 1024.0f) - mu2 * mu2 + 1e-5f);
#pragma unroll
    for (int i2 = 0; i2 < 4; ++i2) {
      const int d = i2 * 256 + l4;
      float4 g = *(const float4*)(gamma + d);
      float4 bb = *(const float4*)(beta + d);
      ushort4 u;
      u.x = f2bf((agg[i2].x - mu2) * rstd2 * g.x + bb.x);
      u.y = f2bf((agg[i2].y - mu2) * rstd2 * g.y + bb.y);
      u.z = f2bf((agg[i2].z - mu2) * rstd2 * g.z + bb.z);
      u.w = f2bf((agg[i2].w - mu2) * rstd2 * g.w + bb.w);
      *(ushort4*)(lnagg + (size_t)b * D + d) = u;
    }
  }
}

// ---------------- K2: bf16 MFMA GEMM + fused epilogue ----------------
__global__ __launch_bounds__(256) void k2_gemm_ep(
    const unsigned short* __restrict__ A,   // lnagg bf16 [8192][1024]
    const unsigned short* __restrict__ Bw,  // W_layer bf16 [1024][1024]
    const float* __restrict__ blayer,
    const float* __restrict__ xs,
    const float* __restrict__ hres_g, const float* __restrict__ hpost_g,
    float* __restrict__ outMean, float* __restrict__ outUpd) {
  __shared__ char smem[44032];
  char* AsB = smem;            // 16384 B: 128 rows x 64 bf16 (8 chunks of 16B)
  char* BsB = smem + 16384;    // 16384 B
  float* EP = (float*)smem;    // epilogue overlay: 32 x 132 fp32 = 16896 B
  float* HR = (float*)(smem + 32768);  // 128 x 17
  float* HP = (float*)(smem + 41472);  // 128 x 5

  const int tid = threadIdx.x;
  const int l = tid & 63;
  const int wv = tid >> 6;
  const int wm = wv >> 1, wn = wv & 1;
  const int lrow = l & 15, lq = l >> 4;
  const int bm0 = blockIdx.x * 128;
  const int bn0 = blockIdx.y * 128;

#pragma unroll
  for (int i = 0; i < 8; ++i) {
    int idx = i * 256 + tid;  // 0..2047
    HR[(idx >> 4) * 17 + (idx & 15)] = hres_g[(size_t)bm0 * 16 + idx];
  }
#pragma unroll
  for (int i = 0; i < 2; ++i) {
    int idx = i * 256 + tid;  // 0..511
    HP[(idx >> 2) * 5 + (idx & 3)] = hpost_g[(size_t)bm0 * 4 + idx];
  }

  f32x4 acc[4][4] = {};

#pragma unroll 1
  for (int kt = 0; kt < 16; ++kt) {
    __syncthreads();
#pragma unroll
    for (int c = 0; c < 4; ++c) {
      const int idx = c * 256 + tid;              // 16B-chunk index 0..1023
      const int row = idx >> 3, cc = idx & 7;
      const int gch = cc ^ (row & 7);             // XOR swizzle on global side
      async_ld16((const char*)A + ((size_t)(bm0 + row) << 11) + kt * 128 + gch * 16,
                 AsB + idx * 16);
      async_ld16((const char*)Bw + ((size_t)(bn0 + row) << 11) + kt * 128 + gch * 16,
                 BsB + idx * 16);
    }
    __syncthreads();
#pragma unroll
    for (int kk = 0; kk < 2; ++kk) {
      bf16x8 af[4], bfr[4];
      const int sw = (kk * 4 + lq);
#pragma unroll
      for (int t = 0; t < 4; ++t) {
        const int ra = wm * 64 + t * 16 + lrow;
        const int rbr = wn * 64 + t * 16 + lrow;
        af[t] = *(const bf16x8*)(AsB + ra * 128 + (sw ^ (ra & 7)) * 16);
        bfr[t] = *(const bf16x8*)(BsB + rbr * 128 + (sw ^ (rbr & 7)) * 16);
      }
#pragma unroll
      for (int ti = 0; ti < 4; ++ti)
#pragma unroll
        for (int tj = 0; tj < 4; ++tj)
          acc[ti][tj] =
              __builtin_amdgcn_mfma_f32_16x16x32_bf16(af[ti], bfr[tj], acc[ti][tj], 0, 0, 0);
    }
  }

  // ---- epilogue: 4 chunks of 32 rows; LDS transpose then nt-vector stream
#pragma unroll
  for (int ti = 0; ti < 4; ++ti) {
    __syncthreads();
#pragma unroll
    for (int tj = 0; tj < 4; ++tj)
#pragma unroll
      for (int r2 = 0; r2 < 4; ++r2)
        EP[(wm * 16 + lq * 4 + r2) * 132 + wn * 64 + tj * 16 + lrow] = acc[ti][tj][r2];
    __syncthreads();

    const int rr2 = tid >> 3;        // 0..31
    const int c0 = (tid & 7) * 4;    // first float4 col, stride 32 over k2i
    const int bl = (rr2 >> 4) * 64 + ti * 16 + (rr2 & 15);
    const int gr = bm0 + bl;
    float hr[16], hp4[4];
#pragma unroll
    for (int q = 0; q < 16; ++q) hr[q] = HR[bl * 17 + q];
#pragma unroll
    for (int q = 0; q < 4; ++q) hp4[q] = HP[bl * 5 + q];
    const float cm0 = 0.25f * (hr[0] + hr[4] + hr[8] + hr[12]);
    const float cm1 = 0.25f * (hr[1] + hr[5] + hr[9] + hr[13]);
    const float cm2 = 0.25f * (hr[2] + hr[6] + hr[10] + hr[14]);
    const float cm3 = 0.25f * (hr[3] + hr[7] + hr[11] + hr[15]);
    const float hps = 0.25f * (hp4[0] + hp4[1] + hp4[2] + hp4[3]);
    const float* xb = xs + (size_t)gr * SD + bn0;
    float* um = outMean + (size_t)gr * 1024 + bn0;
    float* uu = outUpd + (size_t)gr * 4096 + bn0;
#pragma unroll
    for (int k2i = 0; k2i < 4; ++k2i) {
      const int col = c0 + k2i * 32;
      f32x4 ov = *(const f32x4*)(EP + rr2 * 132 + col);
      ov += *(const f32x4*)(blayer + bn0 + col);
      const f32x4 x0 = *(const f32x4*)(xb + col);
      const f32x4 x1 = *(const f32x4*)(xb + 1024 + col);
      const f32x4 x2 = *(const f32x4*)(xb + 2048 + col);
      const f32x4 x3 = *(const f32x4*)(xb + 3072 + col);
      __builtin_nontemporal_store(cm0 * x0 + cm1 * x1 + cm2 * x2 + cm3 * x3 + ov * hps,
                                  (f32x4*)(um + col));
      __builtin_nontemporal_store(hr[0] * x0 + hr[1] * x1 + hr[2] * x2 + hr[3] * x3 + ov * hp4[0],
                                  (f32x4*)(uu + col));
      __builtin_nontemporal_store(hr[4] * x0 + hr[5] * x1 + hr[6] * x2 + hr[7] * x3 + ov * hp4[1],
                                  (f32x4*)(uu + 1024 + col));
      __builtin_nontemporal_store(hr[8] * x0 + hr[9] * x1 + hr[10] * x2 + hr[11] * x3 + ov * hp4[2],
                                  (f32x4*)(uu + 2048 + col));
      __builtin_nontemporal_store(hr[12] * x0 + hr[13] * x1 + hr[14] * x2 + hr[15] * x3 + ov * hp4[3],
                                  (f32x4*)(uu + 3072 + col));
    }
  }
}

// ---------------- launch ----------------
extern "C" void kernel_launch(void* const* d_in, const int* in_sizes, int n_in,
                              void* d_out, int out_size, void* d_ws, size_t ws_size,
                              hipStream_t stream) {
  const float* xs = (const float*)d_in[1];
  const float* Wpre = (const float*)d_in[2];
  const float* bpre = (const float*)d_in[3];
  const float* Wpost = (const float*)d_in[4];
  const float* bpost = (const float*)d_in[5];
  const float* Wres = (const float*)d_in[6];
  const float* bres = (const float*)d_in[7];
  const float* apre = (const float*)d_in[8];
  const float* apost = (const float*)d_in[9];
  const float* ares = (const float*)d_in[10];
  const float* gamma = (const float*)d_in[11];
  const float* beta = (const float*)d_in[12];
  const float* Wlayer = (const float*)d_in[13];
  const float* blayer = (const float*)d_in[14];

  const size_t OFF_LNAGG = (size_t)2 << 20;                     // 16 MB
  const size_t OFF_HRES = (size_t)18 << 20;                     // 512 KB
  const size_t OFF_HPOST = OFF_HRES + (size_t)BROWS * 16 * 4;   // 128 KB
  const size_t OFF_WSUM = OFF_HPOST + (size_t)BROWS * 4 * 4;    // 512 B
  const size_t OFF_WALL = OFF_WSUM + 512;                       // 384 KB
  const size_t NEED = OFF_WALL + (size_t)24 * SD * 4;
  if (ws_size < NEED) return;  // workspace too small — fail visibly

  char* ws = (char*)d_ws;
  unsigned short* wl16 = (unsigned short*)ws;
  unsigned short* lnagg = (unsigned short*)(ws + OFF_LNAGG);
  float* hresb = (float*)(ws + OFF_HRES);
  float* hpostb = (float*)(ws + OFF_HPOST);
  float* wsum = (float*)(ws + OFF_WSUM);
  float* Wall = (float*)(ws + OFF_WALL);

  float* outMean = (float*)d_out;
  float* outUpd = outMean + (size_t)BROWS * D;

  hipLaunchKernelGGL(k0_prep, dim3(1048), dim3(256), 0, stream, Wlayer, Wpre, Wpost, Wres,
                     wl16, Wall, wsum);
  hipLaunchKernelGGL(k1_rowpass, dim3(2048), dim3(256), 0, stream, xs, Wall, bpre, bpost,
                     bres, apre, apost, ares, gamma, beta, wsum, lnagg, hresb, hpostb);
  hipLaunchKernelGGL(k2_gemm_ep, dim3(64, 8), dim3(256), 0, stream, lnagg, wl16, blayer, xs,
                     hresb, hpostb, outMean, outUpd);
}